// Round 2
// baseline (78.682 us; speedup 1.0000x reference)
//
#include <hip/hip_runtime.h>

#define THREADS 256
#define PB 4                 // puzzles per block-iteration (PB*729 floats = 16B-aligned)

__global__ __launch_bounds__(THREADS) void sudoku_main(
    const float* __restrict__ logits,
    const int*   __restrict__ targets,
    const int*   __restrict__ puzzles,
    float* __restrict__ acc,
    int B)
{
  __shared__ float lds[PB * 729];       // logits, then masked probs in-place (11664 B)
  __shared__ float sred[4][5];

  const int tid = threadIdx.x;
  const int numGroups = (B + PB - 1) / PB;

  float a_focal = 0.f, a_ent = 0.f, a_msk = 0.f, a_uniq = 0.f, a_sq = 0.f;

  for (int g = blockIdx.x; g < numGroups; g += gridDim.x) {
    const int grp = min(PB, B - g * PB);      // puzzles in this group (PB except maybe tail)
    const int nf  = grp * 729;                // floats to stage

    // ---- stage logits: coalesced float4 global -> LDS ----
    {
      const float4* src4 = (const float4*)(logits + (size_t)g * (PB * 729));
      float4* dst4 = (float4*)lds;
      const int nf4 = nf >> 2;
#pragma unroll
      for (int r = 0; r < (PB * 729 / 4 + THREADS - 1) / THREADS; ++r) {
        int idx = tid + r * THREADS;
        if (idx < nf4) dst4[idx] = src4[idx];
      }
      int remBase = nf4 << 2;
      if (tid < (nf - remBase))
        lds[remBase + tid] = logits[(size_t)g * (PB * 729) + remBase + tid];
    }
    __syncthreads();

    // ---- phase A: per-cell softmax / focal / entropy / top-2 ----
#pragma unroll
    for (int r = 0; r < (PB * 81 + THREADS - 1) / THREADS; ++r) {
      int c = tid + r * THREADS;
      if (c < grp * 81) {
        const size_t cidx = (size_t)g * (PB * 81) + c;
        int tg = targets[cidx] - 1;           // coalesced dword
        int pz = puzzles[cidx];               // coalesced dword
        tg = tg < 0 ? 0 : (tg > 8 ? 8 : tg);

        float l[9];
#pragma unroll
        for (int i = 0; i < 9; ++i) l[i] = lds[c * 9 + i];   // stride-9 words: conflict-free
        float m = l[0];
#pragma unroll
        for (int i = 1; i < 9; ++i) m = fmaxf(m, l[i]);
        float e[9], s = 0.f, lsum = 0.f, e1 = -1.f, e2 = -1.f;
#pragma unroll
        for (int i = 0; i < 9; ++i) {
          float x  = l[i] - m;
          float ei = __expf(x);
          e[i] = ei;
          s += ei;
          lsum += ei * x;
          if (ei > e1) { e2 = e1; e1 = ei; }
          else if (ei > e2) { e2 = ei; }
        }
        float inv_s = 1.f / s;
        float logs  = __logf(s);

        float lpt   = (l[tg] - m) - logs;     // log p_target
        float pt    = e[tg] * inv_s;
        float om    = 1.f - pt;
        float focal = om * om * (-lpt);

        float ent = logs - lsum * inv_s;      // -(sum p*log p)
        float gap = (e1 - e2) * inv_s;
        float uq  = fmaxf(0.f, 1.f - gap);

        float mk = (pz == 0) ? 1.f : 0.f;
        a_focal += focal * mk;
        a_ent   += ent * mk;
        a_msk   += mk;
        a_uniq  += uq;                        // uniqueness is unmasked

        float pm = inv_s * mk;
#pragma unroll
        for (int i = 0; i < 9; ++i) lds[c * 9 + i] = e[i] * pm;  // own slots, in-place
      }
    }
    __syncthreads();

    // ---- phase C: 243 unit-sums (row/col/box x 9units x 9ch) per puzzle ----
#pragma unroll
    for (int r = 0; r < (PB * 243 + THREADS - 1) / THREADS; ++r) {
      int s = tid + r * THREADS;
      if (s < grp * 243) {
        int lp = s / 243;
        int u  = s - lp * 243;
        int ut = u / 81;                      // 0=row,1=col,2=box
        int v  = u - ut * 81;
        int uidx = v / 9;
        int uch  = v - uidx * 9;
        int base = lp * 729;
        float ssum = 0.f;
#pragma unroll
        for (int j = 0; j < 9; ++j) {
          int cell;
          if (ut == 0)      cell = uidx * 9 + j;
          else if (ut == 1) cell = j * 9 + uidx;
          else              cell = (uidx / 3) * 27 + (uidx % 3) * 3
                                   + (j / 3) * 9 + (j % 3);
          ssum += lds[base + cell * 9 + uch];
        }
        float d = ssum - 1.f;
        a_sq += d * d;
      }
    }
    __syncthreads();
  }

  // ---- wave (64-lane) + block reduction, one atomicAdd set per block ----
#pragma unroll
  for (int off = 32; off > 0; off >>= 1) {
    a_focal += __shfl_down(a_focal, off);
    a_ent   += __shfl_down(a_ent,   off);
    a_msk   += __shfl_down(a_msk,   off);
    a_uniq  += __shfl_down(a_uniq,  off);
    a_sq    += __shfl_down(a_sq,    off);
  }
  const int wave = tid >> 6;
  if ((tid & 63) == 0) {
    sred[wave][0] = a_focal; sred[wave][1] = a_ent; sred[wave][2] = a_msk;
    sred[wave][3] = a_uniq;  sred[wave][4] = a_sq;
  }
  __syncthreads();
  if (tid < 5) {
    float v = sred[0][tid] + sred[1][tid] + sred[2][tid] + sred[3][tid];
    atomicAdd(&acc[tid], v);
  }
}

__global__ void sudoku_finalize(const float* __restrict__ acc,
                                float* __restrict__ out, float invBG)
{
  float focal = acc[0], ent = acc[1], msum = acc[2], uniq = acc[3], sq = acc[4];
  float inv_m = 1.f / (msum + 1e-8f);
  float ce    = focal * inv_m;
  float entl  = 0.1f * ent * inv_m;
  float uql   = 0.1f * uniq * invBG;
  float rcb   = sq * invBG;    // (row+col+box) means share denominator B*81
  float constraint = (rcb + entl + uql) * 0.2f;
  out[0] = ce + 0.5f * constraint;
}

extern "C" void kernel_launch(void* const* d_in, const int* in_sizes, int n_in,
                              void* d_out, int out_size, void* d_ws, size_t ws_size,
                              hipStream_t stream)
{
  (void)n_in; (void)out_size; (void)ws_size;
  const float* logits  = (const float*)d_in[0];
  const int*   targets = (const int*)d_in[1];
  const int*   puzzles = (const int*)d_in[2];
  float* out = (float*)d_out;
  float* acc = (float*)d_ws;

  const int B = in_sizes[0] / 729;           // B*9*9*9 logits
  const int numGroups = (B + PB - 1) / PB;

  hipMemsetAsync(acc, 0, 5 * sizeof(float), stream);

  int grid = numGroups < 2048 ? numGroups : 2048;
  sudoku_main<<<grid, THREADS, 0, stream>>>(logits, targets, puzzles, acc, B);

  const float invBG = 1.f / ((float)B * 81.f);
  sudoku_finalize<<<1, 1, 0, stream>>>(acc, out, invBG);
}